// Round 11
// baseline (327.423 us; speedup 1.0000x reference)
//
#include <hip/hip_runtime.h>

#define NUM_CODES 4096
#define CODE_DIM  64
#define NPTS      65536              // B*S = 16*4096
#define NTILES    (NUM_CODES / 16)   // 256 code tiles
#define NSEG2     16                 // code segments in scan
#define SEGTILES  (NTILES / NSEG2)   // 16 tiles per segment
#define NCOPY     8                  // XCD-local accumulator copies
#define DECAYF    0.99f
#define EPSF      1e-5f
#define BIASF     160.0f             // positive & small exponent (x_sq << 160)
#define THRF      0.02f              // quantum .0078 + 2*mfma err .006 + margin

typedef __attribute__((ext_vector_type(8))) short short8v;
typedef __attribute__((ext_vector_type(4))) float f32x4;
#define MFMA16 __builtin_amdgcn_mfma_f32_16x16x32_bf16

__device__ __forceinline__ unsigned med3u(unsigned a, unsigned b, unsigned c) {
    unsigned d;
    asm("v_med3_u32 %0, %1, %2, %3" : "=v"(d) : "v"(a), "v"(b), "v"(c));
    return d;
}
__device__ __forceinline__ unsigned min3u(unsigned a, unsigned b, unsigned c) {
    unsigned d;
    asm("v_min3_u32 %0, %1, %2, %3" : "=v"(d) : "v"(a), "v"(b), "v"(c));
    return d;
}
__device__ __forceinline__ unsigned minu(unsigned a, unsigned b) { return a < b ? a : b; }
__device__ __forceinline__ unsigned maxu(unsigned a, unsigned b) { return a > b ? a : b; }

#define UPDL(v, c, M1, I1, M2, I2) do{ \
    bool lt1_ = (v) < (M1) || ((v) == (M1) && (c) < (I1)); \
    bool lt2_ = (v) < (M2) || ((v) == (M2) && (c) < (I2)); \
    if (lt1_) { M2 = M1; I2 = I1; M1 = (v); I1 = (c); } \
    else if (lt2_) { M2 = (v); I2 = (c); } } while(0)

// ---------------- workspace layout (float indices) ----------------
#define WS_BC   0                        // 8 x 4096 batch_cluster copies
#define WS_ES   32768                    // 8 x 262144 embed_sum copies
#define WS_N    2129920                  // 1  n (precomputed)
#define WS_CNT  2129921                  // 1  flagged count (int)
#define WS_CSQ  2129924                  // 4096 csq+BIAS (16B aligned)
#define WS_CF   2134020                  // 262144 floats A-frag codebook
#define WS_TOP2 2396164                  // 16 segs x 65536 uint2 (= 2097152 floats)
// flagged list overlays WS_CF (dead after scan)

// ---------------- output layout ----------------
#define OUT_Q    0
#define OUT_IDX  4194304
#define OUT_CB   4259840
#define OUT_CS   4521984
#define OUT_EMA  4526080

__device__ __forceinline__ unsigned short f2bf(float f) {
    unsigned u = __float_as_uint(f);
    u += 0x7FFFu + ((u >> 16) & 1u);
    return (unsigned short)(u >> 16);
}
__device__ __forceinline__ float bf2f(unsigned short h) {
    return __uint_as_float(((unsigned)h) << 16);
}

// ---------- prep: csq(+bias) + bf16 hi/lo A-frags + n scalar ----------
__global__ __launch_bounds__(256) void prep_all(const float* __restrict__ cb,
                                                const float* __restrict__ cs_in,
                                                float* __restrict__ csq,
                                                short* __restrict__ cf,
                                                float* __restrict__ n_out) {
    if (blockIdx.x == 128) {
        __shared__ float ws4[4];
        int tid = threadIdx.x;
        float s = 0.f;
#pragma unroll
        for (int j = 0; j < 16; ++j) s += cs_in[tid + 256 * j];
#pragma unroll
        for (int off = 32; off > 0; off >>= 1) s += __shfl_down(s, off);
        if ((tid & 63) == 0) ws4[tid >> 6] = s;
        __syncthreads();
        if (tid == 0)
            n_out[0] = DECAYF * (ws4[0] + ws4[1] + ws4[2] + ws4[3])
                     + (1.0f - DECAYF) * (float)NPTS;
        return;
    }
    int t     = blockIdx.x * 256 + threadIdx.x;   // 32768 threads
    int code  = t >> 3;
    int chunk = t & 7;
    int khalf = chunk >> 2;
    int g     = chunk & 3;
    const float* src = cb + (size_t)code * CODE_DIM + khalf * 32 + g * 8;
    float4 v0 = *(const float4*)(src);
    float4 v1 = *(const float4*)(src + 4);
    float f[8] = {v0.x, v0.y, v0.z, v0.w, v1.x, v1.y, v1.z, v1.w};
    float sq = 0.f;
    short8v H, L;
#pragma unroll
    for (int j = 0; j < 8; ++j) {
        sq = fmaf(f[j], f[j], sq);
        float s = -2.0f * f[j];
        unsigned short hb = f2bf(s);
        H[j] = (short)hb;
        L[j] = (short)f2bf(s - bf2f(hb));
    }
#pragma unroll
    for (int off = 1; off < 8; off <<= 1) sq += __shfl_xor(sq, off);
    if (chunk == 0) csq[code] = sq + BIASF;
    int ctile = code >> 4;
    int lane_in_frag = g * 16 + (code & 15);
    *(short8v*)(cf + ((size_t)(ctile * 4 + khalf) * 64 + lane_in_frag) * 8)     = H;
    *(short8v*)(cf + ((size_t)(ctile * 4 + 2 + khalf) * 64 + lane_in_frag) * 8) = L;
}

// ---------- MFMA scan: block = 4 waves = 4 code-segments of one 64-pt group ----------
// Fold: u32 packed keys (biased f32 bits | 8-bit lane-local index tile:4|grp:2|r:2)
__global__ __launch_bounds__(256) void scan_mfma(const float* __restrict__ x,
                                                 const short* __restrict__ cf,
                                                 const float* __restrict__ csq,
                                                 uint2* __restrict__ top2) {
    const int wid  = threadIdx.x >> 6;           // 0..3
    const int lane = threadIdx.x & 63;
    const int blk  = blockIdx.x;                 // 0..4095
    const int pw   = blk >> 2;                   // point group 0..1023
    const int seg  = (blk & 3) * 4 + wid;        // 0..15
    const int col  = lane & 15;
    const int grp  = lane >> 4;
    const unsigned grpsh = (unsigned)(grp << 2);
    const int pbase = pw * 64;

    // B-frags for 64 points, bf16 hi/lo split in-register.
    short8v xh[4][2], xl[4][2];
#pragma unroll
    for (int t = 0; t < 4; ++t) {
#pragma unroll
        for (int h = 0; h < 2; ++h) {
            const float* xp = x + (size_t)(pbase + t * 16 + col) * CODE_DIM + h * 32 + grp * 8;
            float4 v0 = *(const float4*)(xp);
            float4 v1 = *(const float4*)(xp + 4);
            float f[8] = {v0.x, v0.y, v0.z, v0.w, v1.x, v1.y, v1.z, v1.w};
            short8v H, L;
#pragma unroll
            for (int j = 0; j < 8; ++j) {
                unsigned short hb = f2bf(f[j]);
                H[j] = (short)hb;
                L[j] = (short)f2bf(f[j] - bf2f(hb));
            }
            xh[t][h] = H; xl[t][h] = L;
        }
    }

    unsigned m1k[4], m2k[4];
#pragma unroll
    for (int t = 0; t < 4; ++t) { m1k[t] = 0xFFFFFFFFu; m2k[t] = 0xFFFFFFFFu; }

#define LOAD_TILE(CT, AF, CQ) do { \
    const short* p_ = cf + ((size_t)(CT) * 4 * 64 + lane) * 8; \
    AF[0] = *(const short8v*)(p_); \
    AF[1] = *(const short8v*)(p_ + 64 * 8); \
    AF[2] = *(const short8v*)(p_ + 2 * 64 * 8); \
    AF[3] = *(const short8v*)(p_ + 3 * 64 * 8); \
    CQ = *(const f32x4*)(csq + (CT) * 16 + grp * 4); } while(0)

#define COMPUTE_TILE(CT, AF, CQ) do { \
    const unsigned tb8_ = (unsigned)(((CT) - tb) << 4) | grpsh; \
    unsigned idx_[4] = {tb8_, tb8_ | 1u, tb8_ | 2u, tb8_ | 3u}; \
    _Pragma("unroll") \
    for (int t = 0; t < 4; ++t) { \
        f32x4 a = CQ; \
        a = MFMA16(AF[0], xh[t][0], a, 0, 0, 0); \
        a = MFMA16(AF[1], xh[t][1], a, 0, 0, 0); \
        a = MFMA16(AF[0], xl[t][0], a, 0, 0, 0); \
        a = MFMA16(AF[1], xl[t][1], a, 0, 0, 0); \
        a = MFMA16(AF[2], xh[t][0], a, 0, 0, 0); \
        a = MFMA16(AF[3], xh[t][1], a, 0, 0, 0); \
        _Pragma("unroll") \
        for (int r = 0; r < 4; ++r) { \
            unsigned key = (__float_as_uint(a[r]) & 0xFFFFFF00u) | idx_[r]; \
            m2k[t] = med3u(m1k[t], m2k[t], key); \
            m1k[t] = minu(m1k[t], key); \
        } \
    } } while(0)

    short8v A0[4], A1[4];
    f32x4 q0, q1;
    const int tb = seg * SEGTILES;
    LOAD_TILE(tb, A0, q0);
#pragma unroll 4
    for (int it = 0; it < SEGTILES / 2; ++it) {
        const int t0 = tb + 2 * it, t1 = t0 + 1;
        const int t2 = (2 * it + 2 < SEGTILES) ? t1 + 1 : tb;
        LOAD_TILE(t1, A1, q1);
        COMPUTE_TILE(t0, A0, q0);
        LOAD_TILE(t2, A0, q0);
        COMPUTE_TILE(t1, A1, q1);
    }
#undef LOAD_TILE
#undef COMPUTE_TILE

    // cross-lane merge (keys carry index & code-order tie-break)
#pragma unroll
    for (int t = 0; t < 4; ++t) {
#pragma unroll
        for (int off = 16; off <= 32; off <<= 1) {
            unsigned o1 = __shfl_xor(m1k[t], off);
            unsigned o2 = __shfl_xor(m2k[t], off);
            m2k[t] = min3u(maxu(m1k[t], o1), m2k[t], o2);
            m1k[t] = minu(m1k[t], o1);
        }
    }
    if (lane < 16) {
#pragma unroll
        for (int t = 0; t < 4; ++t)
            top2[(size_t)seg * NPTS + pbase + t * 16 + lane] = make_uint2(m1k[t], m2k[t]);
    }
}

// ---------- merge segments; certify or flag (wave-aggregated append) ----------
__global__ __launch_bounds__(256) void emit1(const uint2* __restrict__ top2,
                                             float* __restrict__ idx_out,
                                             float* __restrict__ bc_acc,
                                             int* __restrict__ flagged,
                                             int* __restrict__ cnt) {
    const int p = blockIdx.x * 256 + threadIdx.x;
    const int lane = threadIdx.x & 63;
    unsigned M1 = 0xFFFFFFFFu, M2 = 0xFFFFFFFFu;
    int wseg = 0;
#pragma unroll
    for (int s = 0; s < NSEG2; ++s) {
        uint2 t = top2[(size_t)s * NPTS + p];
        M2 = min3u(maxu(M1, t.x), M2, t.y);
        if (t.x < M1) wseg = s;
        M1 = minu(M1, t.x);
    }
    float m1v = __uint_as_float(M1 & 0xFFFFFF00u);
    float m2v = __uint_as_float(M2 & 0xFFFFFF00u);
    unsigned bits = M1 & 0xFFu;
    int code = (wseg * SEGTILES + (int)(bits >> 4)) * 16 + (int)((bits >> 2) & 3u) * 4 + (int)(bits & 3u);

    bool certified = (m2v - m1v >= THRF);
    if (certified) {
        idx_out[p] = (float)code;
        atomicAdd(&bc_acc[(blockIdx.x & (NCOPY - 1)) * NUM_CODES + code], 1.0f);
    }
    unsigned long long mask = __ballot(!certified);
    int nw = __popcll(mask);
    int base = 0;
    if (lane == 0 && nw) base = atomicAdd(cnt, nw);
    base = __shfl(base, 0);
    if (!certified) {
        int off = __popcll(mask & ((1ULL << lane) - 1ULL));
        flagged[base + off] = p;
    }
}

// ---------- fallback: wave-per-point exact f32 top-2 + f64 refine of the pair ----------
__global__ __launch_bounds__(256) void fallback_kernel(const float* __restrict__ x,
                                                       const float* __restrict__ cb,
                                                       const int* __restrict__ flagged,
                                                       const int* __restrict__ cnt,
                                                       float* __restrict__ idx_out,
                                                       float* __restrict__ bc_acc) {
    const int wid  = threadIdx.x >> 6;
    const int lane = threadIdx.x & 63;
    const int n = *cnt;
    float* bcc = bc_acc + (size_t)(blockIdx.x & (NCOPY - 1)) * NUM_CODES;
    for (int w = blockIdx.x * 4 + wid; w < n; w += 2048) {
        const int p = flagged[w];
        const float4* xp = (const float4*)(x + (size_t)p * CODE_DIM);
        float4 xv[16];
#pragma unroll
        for (int q = 0; q < 16; ++q) xv[q] = xp[q];

        float m1 = 3e38f, m2 = 3e38f;
        int   i1 = 0,     i2 = 0;
        for (int j = 0; j < 64; ++j) {
            const int c = lane + 64 * j;   // ascending per lane
            const float4* cp = (const float4*)(cb + (size_t)c * CODE_DIM);
            float a0 = 0.f, a1 = 0.f, a2 = 0.f, a3 = 0.f;
#pragma unroll
            for (int q = 0; q < 16; ++q) {
                float4 cv = cp[q];
                float d0 = xv[q].x - cv.x;
                float d1 = xv[q].y - cv.y;
                float d2 = xv[q].z - cv.z;
                float d3 = xv[q].w - cv.w;
                a0 = fmaf(d0, d0, a0);
                a1 = fmaf(d1, d1, a1);
                a2 = fmaf(d2, d2, a2);
                a3 = fmaf(d3, d3, a3);
            }
            float acc = (a0 + a1) + (a2 + a3);
            if (acc < m1)      { m2 = m1; i2 = i1; m1 = acc; i1 = c; }
            else if (acc < m2) { m2 = acc; i2 = c; }
        }
        // cross-lane top-2 merge (lexicographic)
#pragma unroll
        for (int off = 1; off < 64; off <<= 1) {
            float om1 = __shfl_xor(m1, off); int oi1 = __shfl_xor(i1, off);
            float om2 = __shfl_xor(m2, off); int oi2 = __shfl_xor(i2, off);
            UPDL(om1, oi1, m1, i1, m2, i2);
            UPDL(om2, oi2, m1, i1, m2, i2);
        }
        // f64 refine of the two candidates, lane-per-dim
        double xd  = (double)x[(size_t)p * CODE_DIM + lane];
        double c1d = (double)cb[(size_t)i1 * CODE_DIM + lane];
        double c2d = (double)cb[(size_t)i2 * CODE_DIM + lane];
        double d1 = xd - c1d, d2 = xd - c2d;
        double e1 = d1 * d1, e2 = d2 * d2;
#pragma unroll
        for (int off = 1; off < 64; off <<= 1) {
            e1 += __shfl_xor(e1, off);
            e2 += __shfl_xor(e2, off);
        }
        if (lane == 0) {
            int fin;
            if (e1 < e2)      fin = i1;
            else if (e2 < e1) fin = i2;
            else              fin = (i1 < i2) ? i1 : i2;
            idx_out[p] = (float)fin;
            atomicAdd(&bcc[fin], 1.0f);
        }
    }
}

// ---------- quantized write + embed_sum scatter (XCD-local copy) ----------
__global__ __launch_bounds__(256) void emit2(const float* __restrict__ x,
                                             const float* __restrict__ cb,
                                             const float* __restrict__ idx_out,
                                             float* __restrict__ q_out,
                                             float* __restrict__ es_acc) {
    const int p    = blockIdx.x * 4 + (threadIdx.x >> 6);
    const int lane = threadIdx.x & 63;
    const int fin  = (int)idx_out[p];
    float* esc = es_acc + (size_t)(blockIdx.x & (NCOPY - 1)) * (NUM_CODES * CODE_DIM);
    float xv = x[(size_t)p * CODE_DIM + lane];
    float cv = cb[(size_t)fin * CODE_DIM + lane];
    q_out[(size_t)p * CODE_DIM + lane] = cv;
    atomicAdd(&esc[(size_t)fin * CODE_DIM + lane], xv);
}

// ---------- finalize: sum copies, EMA, smoothed codebook, cs ----------
__global__ __launch_bounds__(256) void finalize_kernel(const float* __restrict__ cs_in,
                                                       const float* __restrict__ ema_in,
                                                       const float* __restrict__ bc_acc,
                                                       const float* __restrict__ es_acc,
                                                       const float* __restrict__ n_ptr,
                                                       float* __restrict__ cs_out,
                                                       float* __restrict__ ema_out,
                                                       float* __restrict__ cb_out) {
    int idx = blockIdx.x * 256 + threadIdx.x;   // 262144 threads
    int k   = idx >> 6;
    float bc = 0.f, es = 0.f;
#pragma unroll
    for (int c = 0; c < NCOPY; ++c) {
        bc += bc_acc[(size_t)c * NUM_CODES + k];
        es += es_acc[(size_t)c * (NUM_CODES * CODE_DIM) + idx];
    }
    float ncs = DECAYF * cs_in[k] + (1.0f - DECAYF) * bc;
    if ((idx & 63) == 0) cs_out[k] = ncs;
    float n = *n_ptr;
    float smoothed = (ncs + EPSF) / (n + (float)NUM_CODES * EPSF) * n;
    float ew = DECAYF * ema_in[idx] + (1.0f - DECAYF) * es;
    ema_out[idx] = ew;
    cb_out[idx]  = ew / smoothed;
}

extern "C" void kernel_launch(void* const* d_in, const int* in_sizes, int n_in,
                              void* d_out, int out_size, void* d_ws, size_t ws_size,
                              hipStream_t stream) {
    const float* x    = (const float*)d_in[0];
    const float* cb   = (const float*)d_in[1];
    const float* cs   = (const float*)d_in[2];
    const float* emaw = (const float*)d_in[3];
    float* out = (float*)d_out;
    float* ws  = (float*)d_ws;

    // zero bc copies + es copies + n + cnt (contiguous)
    hipMemsetAsync(ws, 0, (size_t)(WS_CNT + 1) * sizeof(float), stream);

    prep_all<<<129, 256, 0, stream>>>(cb, cs, ws + WS_CSQ, (short*)(ws + WS_CF), ws + WS_N);

    scan_mfma<<<(NPTS / 64) * NSEG2 / 4, 256, 0, stream>>>(
        x, (const short*)(ws + WS_CF), ws + WS_CSQ, (uint2*)(ws + WS_TOP2));

    emit1<<<NPTS / 256, 256, 0, stream>>>(
        (const uint2*)(ws + WS_TOP2), out + OUT_IDX, ws + WS_BC,
        (int*)(ws + WS_CF), (int*)(ws + WS_CNT));

    fallback_kernel<<<512, 256, 0, stream>>>(
        x, cb, (const int*)(ws + WS_CF), (const int*)(ws + WS_CNT),
        out + OUT_IDX, ws + WS_BC);

    emit2<<<NPTS / 4, 256, 0, stream>>>(
        x, cb, out + OUT_IDX, out + OUT_Q, ws + WS_ES);

    finalize_kernel<<<(NUM_CODES * CODE_DIM) / 256, 256, 0, stream>>>(
        cs, emaw, ws + WS_BC, ws + WS_ES, ws + WS_N,
        out + OUT_CS, out + OUT_EMA, out + OUT_CB);
}